// Round 1
// 1918.381 us; speedup vs baseline: 1.3772x; 1.3772x over previous
//
#include <hip/hip_runtime.h>
#include <hip/hip_bf16.h>
#include <cstdint>

// Problem constants (Experts FFN): W=8, E=4, C=2048, H=1024, DFF=4096
#define W_   8
#define E_   4
#define C_   2048
#define H_   1024
#define DFF_ 4096

typedef unsigned short u16;
typedef __attribute__((ext_vector_type(8))) short bf16x8;   // 8 bf16 = 4 VGPRs
typedef __attribute__((ext_vector_type(4))) float f32x4;    // MFMA 16x16 accumulator

// ---------- helpers ----------
__device__ __forceinline__ u16 f2bf(float f) {
  union { float f; uint32_t u; } v; v.f = f;
  uint32_t u = v.u;
  uint32_t r = (u + 0x7FFFu + ((u >> 16) & 1u)) >> 16;  // RNE
  return (u16)r;
}

// async global->LDS, 16B per lane; LDS dest = wave-uniform base + lane*16
__device__ __forceinline__ void async_cp16(const u16* g, u16* l) {
  __builtin_amdgcn_global_load_lds(
      (__attribute__((address_space(1))) void*)(g),
      (__attribute__((address_space(3))) void*)(l),
      16, 0, 0);
}

// ---------- conversion kernels (unchanged) ----------
__global__ __launch_bounds__(256) void cvt_x_kernel(const float* __restrict__ in,
                                                    u16* __restrict__ out, long n) {
  long i = ((long)blockIdx.x * 256 + threadIdx.x) * 4;
  if (i < n) {
    float4 v = *(const float4*)&in[i];
    ushort4 o;
    o.x = f2bf(v.x); o.y = f2bf(v.y); o.z = f2bf(v.z); o.w = f2bf(v.w);
    *(ushort4*)&out[i] = o;
  }
}

// in: fp32 [E][R][Cn]  ->  out: bf16 [E][Cn][R]   (B^T layout)
__global__ __launch_bounds__(256) void transpose_cvt_kernel(const float* __restrict__ in,
                                                            u16* __restrict__ out,
                                                            int R, int Cn) {
  __shared__ u16 tile[32][33];
  const int e  = blockIdx.z;
  const int c0 = blockIdx.x * 32;
  const int r0 = blockIdx.y * 32;
  const float* inp = in + (size_t)e * R * Cn;
  u16* outp = out + (size_t)e * R * Cn;
  const int tx = threadIdx.x;   // 0..31
  const int ty = threadIdx.y;   // 0..7
#pragma unroll
  for (int j = ty; j < 32; j += 8)
    tile[j][tx] = f2bf(inp[(size_t)(r0 + j) * Cn + (c0 + tx)]);
  __syncthreads();
#pragma unroll
  for (int j = ty; j < 32; j += 8)
    outp[(size_t)(c0 + j) * R + (r0 + tx)] = tile[tx][j];
}

// ---------- 256x256 GEMM, BK=64, 512 threads (8 waves 2Mx4N) ----------
// C[M,N] = A[M,K] * Bt[N,K]^T (+bias, opt GELU).
// Deep pipeline: stage tile kt+1 at top of iter kt (earliest point with 2 LDS
// buffers); the only wait is the iteration-ending __syncthreads() drain, after
// 64 MFMA/wave -> load latency fully covered. One barrier per K-tile.
// LDS swizzle: LDS[row][slot] = G[row][slot ^ (row&7)] (slot = 16B chunk);
// achieved by pre-swizzling the per-lane GLOBAL source (global_load_lds writes
// linearly), read side applies the same XOR -> conflict-free ds_read_b128.
template<bool GELU, int K, int N>
__global__ __launch_bounds__(512, 2) void gemm256_kernel(
    const u16* __restrict__ A0, const u16* __restrict__ B0,
    const float* __restrict__ bias0, void* __restrict__ C0) {

  // T1: bijective chunked XCD swizzle (nwg % 8 == 0 for all our grids)
  const int gx = gridDim.x, gy = gridDim.y;
  const unsigned nwg = (unsigned)(gx * gy * gridDim.z);
  const unsigned L = blockIdx.x + (unsigned)gx * (blockIdx.y + (unsigned)gy * blockIdx.z);
  const unsigned lg = (L & 7u) * (nwg >> 3) + (L >> 3);
  const int bx = (int)(lg % (unsigned)gx);
  const unsigned t1 = lg / (unsigned)gx;
  const int by = (int)(t1 % (unsigned)gy);
  const int bz = (int)(t1 / (unsigned)gy);

  const int g = bz;
  const int e = g & (E_ - 1);
  const u16*  A    = A0 + (size_t)g * C_ * K;
  const u16*  B    = B0 + (size_t)e * (size_t)N * K;
  const float* bias = bias0 + (size_t)e * N;
  u16*   Cb = (u16*)C0  + (size_t)g * C_ * N;
  float* Cf = (float*)C0 + (size_t)g * C_ * N;

  const int rowBase = by * 256;
  const int colBase = bx * 256;

  __shared__ alignas(16) u16 As[2][256 * 64];   // 32 KB per buffer
  __shared__ alignas(16) u16 Bs[2][256 * 64];   // total 128 KB

  const int tid  = threadIdx.x;
  const int wid  = tid >> 6;       // 0..7
  const int lane = tid & 63;
  const int wm   = wid >> 2;       // 0..1  (M half)
  const int wn   = wid & 3;        // 0..3  (N quarter)
  const int l15  = lane & 15;
  const int q    = lane >> 4;      // 0..3
  const int l7   = lane & 7;

  // staging: lane covers row (wid*16 + lane>>3 [+h*128 +i*8]), 16B slot lane&7,
  // source slot pre-swizzled: sslot = (lane&7) ^ (row&7) = (lane&7)^(lane>>3)
  const int srow  = (wid << 4) + (lane >> 3);
  const int sslot = l7 ^ (lane >> 3);
  const u16* gA = A + (size_t)(rowBase + srow) * K + (sslot << 3);
  const u16* gB = B + (size_t)(colBase + srow) * K + (sslot << 3);

  f32x4 acc[8][4] = {};

  const int base_a = ((wm << 7) + l15) << 6;   // (wm*128 + l15) * 64
  const int base_b = ((wn << 6) + l15) << 6;   // (wn*64  + l15) * 64
  const int s0e    = (q ^ l7) << 3;            // swizzled slot elem-offset, ks=0

  constexpr int NK = K >> 6;

  // prologue: stage tile 0 -> buf 0
#pragma unroll
  for (int h = 0; h < 2; ++h)
#pragma unroll
    for (int i = 0; i < 2; ++i) {
      const int r = h * 128 + (wid << 4) + i * 8;
      async_cp16(gA + (size_t)(h * 128 + i * 8) * K, &As[0][r * 64]);
      async_cp16(gB + (size_t)(h * 128 + i * 8) * K, &Bs[0][r * 64]);
    }
  __syncthreads();

  const u16* ga = gA + 64;   // tile 1
  const u16* gb = gB + 64;

  for (int kt = 0; kt < NK; ++kt) {
    const int buf = kt & 1;

    // issue next tile's loads into the idle buffer (earliest legal point)
    if (kt + 1 < NK) {
      u16* la = &As[buf ^ 1][0];
      u16* lb = &Bs[buf ^ 1][0];
#pragma unroll
      for (int h = 0; h < 2; ++h)
#pragma unroll
        for (int i = 0; i < 2; ++i) {
          const int r = h * 128 + (wid << 4) + i * 8;
          async_cp16(ga + (size_t)(h * 128 + i * 8) * K, &la[r * 64]);
          async_cp16(gb + (size_t)(h * 128 + i * 8) * K, &lb[r * 64]);
        }
    }
    ga += 64; gb += 64;

    const u16* Ab = &As[buf][0];
    const u16* Bb = &Bs[buf][0];
#pragma unroll
    for (int ks = 0; ks < 2; ++ks) {
      bf16x8 af[8], bfr[4];
      const int ss = s0e ^ (ks << 5);   // ((ks*4+q)^l7) * 8 elements
#pragma unroll
      for (int mi = 0; mi < 8; ++mi)
        af[mi] = *(const bf16x8*)&Ab[base_a + mi * 1024 + ss];
#pragma unroll
      for (int ni = 0; ni < 4; ++ni)
        bfr[ni] = *(const bf16x8*)&Bb[base_b + ni * 1024 + ss];

      __builtin_amdgcn_s_setprio(1);
#pragma unroll
      for (int mi = 0; mi < 8; ++mi)
#pragma unroll
        for (int ni = 0; ni < 4; ++ni)
          acc[mi][ni] = __builtin_amdgcn_mfma_f32_16x16x32_bf16(
              af[mi], bfr[ni], acc[mi][ni], 0, 0, 0);
      __builtin_amdgcn_s_setprio(0);
    }

    // single drain+barrier per K-tile: waits the loads issued THIS iteration,
    // which had 64 MFMA/wave (~2500 CU-cycles) to land.
    __syncthreads();
  }

  // epilogue — C/D layout: col = lane&15, row = quad*4 + reg (m89/m91-verified)
  float bv[4];
#pragma unroll
  for (int ni = 0; ni < 4; ++ni)
    bv[ni] = bias[colBase + (wn << 6) + ni * 16 + l15];

#pragma unroll
  for (int mi = 0; mi < 8; ++mi) {
#pragma unroll
    for (int ni = 0; ni < 4; ++ni) {
      const int col = colBase + (wn << 6) + ni * 16 + l15;
#pragma unroll
      for (int i = 0; i < 4; ++i) {
        const int row = rowBase + (wm << 7) + mi * 16 + (q << 2) + i;
        float x = acc[mi][ni][i] + bv[ni];
        if (GELU) {
          // jax.nn.gelu default (approximate=True, tanh form)
          const float tt = 0.7978845608028654f * (x + 0.044715f * x * x * x);
          const float ee = __expf(2.0f * tt);
          const float th = 1.0f - 2.0f / (ee + 1.0f);
          Cb[(size_t)row * N + col] = f2bf(0.5f * x * (1.0f + th));
        } else {
          Cf[(size_t)row * N + col] = x;
        }
      }
    }
  }
}

// ---------- launch ----------
extern "C" void kernel_launch(void* const* d_in, const int* in_sizes, int n_in,
                              void* d_out, int out_size, void* d_ws, size_t ws_size,
                              hipStream_t stream) {
  const float* X  = (const float*)d_in[0];
  const float* W1 = (const float*)d_in[1];
  const float* b1 = (const float*)d_in[2];
  const float* W2 = (const float*)d_in[3];
  const float* b2 = (const float*)d_in[4];
  float* out = (float*)d_out;

  char* ws = (char*)d_ws;
  const size_t xb_elems = (size_t)W_ * E_ * C_ * H_;   // 64M
  const size_t w_elems  = (size_t)E_ * H_ * DFF_;      // 16M
  size_t off = 0;
  auto take = [&](size_t bytes) {
    size_t o = off; off += (bytes + 255) & ~(size_t)255; return o;
  };
  const size_t off_x  = take(xb_elems * 2);   // 128 MB
  const size_t off_w1 = take(w_elems * 2);    //  32 MB
  const size_t off_w2 = take(w_elems * 2);    //  32 MB
  u16* Xb  = (u16*)(ws + off_x);
  u16* W1t = (u16*)(ws + off_w1);
  u16* W2t = (u16*)(ws + off_w2);

  const size_t h_per_w = (size_t)E_ * C_ * DFF_ * 2;   // 64 MB per w-slice
  const size_t avail = ws_size > off ? ws_size - off : 0;
  int Wp;                                              // w-slices per pass
  if      (avail >= 8 * h_per_w) Wp = 8;
  else if (avail >= 4 * h_per_w) Wp = 4;
  else if (avail >= 2 * h_per_w) Wp = 2;
  else                           Wp = 1;               // best effort
  u16* Hb = (u16*)(ws + off);

  // one-time conversions (serialized on stream before the GEMM passes)
  cvt_x_kernel<<<dim3((unsigned)(xb_elems / 4 / 256)), dim3(256), 0, stream>>>(
      X, Xb, (long)xb_elems);
  transpose_cvt_kernel<<<dim3(DFF_ / 32, H_ / 32, E_), dim3(32, 8), 0, stream>>>(
      W1, W1t, H_, DFF_);
  transpose_cvt_kernel<<<dim3(H_ / 32, DFF_ / 32, E_), dim3(32, 8), 0, stream>>>(
      W2, W2t, DFF_, H_);

  for (int w0 = 0; w0 < W_; w0 += Wp) {
    const int groups = Wp * E_;
    gemm256_kernel<true, H_, DFF_>
        <<<dim3(DFF_ / 256, C_ / 256, groups), dim3(512), 0, stream>>>(
        Xb + (size_t)w0 * E_ * C_ * H_, W1t, b1, Hb);
    gemm256_kernel<false, DFF_, H_>
        <<<dim3(H_ / 256, C_ / 256, groups), dim3(512), 0, stream>>>(
        Hb, W2t, b2, out + (size_t)w0 * E_ * C_ * H_);
  }
}